// Round 2
// baseline (187.529 us; speedup 1.0000x reference)
//
#include <hip/hip_runtime.h>
#include <hip/hip_fp16.h>
#include <math.h>

typedef _Float16 f16x8 __attribute__((ext_vector_type(8)));
typedef float    f32x4 __attribute__((ext_vector_type(4)));
typedef unsigned short u16;
typedef unsigned int   u32;

#define MFMA_F16(a, b, c) __builtin_amdgcn_mfma_f32_16x16x32_f16((a), (b), (c), 0, 0, 0)

#define NSP 4096
// (1/sqrt(32)) * log2(e): fold softmax scale and exp2 conversion into Q
#define QK_SCALE (0.17677669529663687f * 1.4426950408889634f)

__device__ __forceinline__ float fexp2(float x) {
  return exp2f(x);   // maps to v_exp_f32 under -O3 on amdgcn
}

__device__ __forceinline__ u32 pk_f16(float a, float b) {
#if __has_builtin(__builtin_amdgcn_cvt_pkrtz)
  return __builtin_bit_cast(u32, __builtin_amdgcn_cvt_pkrtz(a, b));
#else
  u16 lo = __builtin_bit_cast(u16, (_Float16)a);
  u16 hi = __builtin_bit_cast(u16, (_Float16)b);
  return (u32)lo | ((u32)hi << 16);
#endif
}

__device__ __forceinline__ u16 f16bits(float a) {
  return __builtin_bit_cast(u16, (_Float16)a);
}

// ---------------------------------------------------------------------------
// Kernel A: QKV projection.  out[384][4096] = [Wq;Wk;Wv][384][256] @ x[256][4096]
// per batch, fp16 MFMA, fp32 accum.  Q,K stored [bh][n][32] (fp16 bits),
// V stored transposed [bh][32][n].  Q pre-scaled by QK_SCALE.
// grid (64 j-tiles, 4 batches) x 512 threads (8 waves, 3 M-tiles of 16 each).
// ---------------------------------------------------------------------------
__global__ __launch_bounds__(512) void qkv_proj_kernel(
    const float* __restrict__ x, const float* __restrict__ Wq,
    const float* __restrict__ Wk, const float* __restrict__ Wv,
    u16* __restrict__ Qo, u16* __restrict__ Ko, u16* __restrict__ Vo)
{
  const int b  = blockIdx.y;
  const int j0 = blockIdx.x * 64;
  const int tid  = threadIdx.x;
  const int wave = tid >> 6, lane = tid & 63;
  const int g = lane >> 4, r = lane & 15;
  const float* xb = x + (size_t)b * 256 * NSP;

  const f32x4 ZERO4 = {0.f, 0.f, 0.f, 0.f};
  f32x4 acc[3][4];
#pragma unroll
  for (int m = 0; m < 3; ++m)
#pragma unroll
    for (int n = 0; n < 4; ++n) acc[m][n] = ZERO4;

  for (int kc = 0; kc < 8; ++kc) {
    f16x8 bfrag[4];
#pragma unroll
    for (int nt = 0; nt < 4; ++nt) {
      const float* src = xb + (size_t)(kc * 32 + g * 8) * NSP + j0 + nt * 16 + r;
      f16x8 f;
#pragma unroll
      for (int i = 0; i < 8; ++i) f[i] = (_Float16)src[(size_t)i * NSP];
      bfrag[nt] = f;
    }
#pragma unroll
    for (int mm = 0; mm < 3; ++mm) {
      const int o_tile = wave * 48 + mm * 16;
      const float* wsrc = (o_tile < 128) ? Wq : ((o_tile < 256) ? Wk : Wv);
      const float* arow = wsrc + ((o_tile & 127) + r) * 256 + kc * 32 + g * 8;
      f16x8 af;
#pragma unroll
      for (int i = 0; i < 8; ++i) af[i] = (_Float16)arow[i];
#pragma unroll
      for (int nt = 0; nt < 4; ++nt)
        acc[mm][nt] = MFMA_F16(af, bfrag[nt], acc[mm][nt]);
    }
  }

  // D layout: row(o) = g*4+i, col(j) = r
#pragma unroll
  for (int mm = 0; mm < 3; ++mm) {
    const int o_tile = wave * 48 + mm * 16;
    const int part = o_tile >> 7;            // 0=Q 1=K 2=V
    const int o_in = o_tile & 127;
    const int head = o_in >> 5;
    const int dbase = (o_in & 31) + g * 4;
#pragma unroll
    for (int nt = 0; nt < 4; ++nt) {
      const int j = j0 + nt * 16 + r;
      if (part < 2) {
        u16* dst = (part == 0) ? Qo : Ko;
        const float sc = (part == 0) ? QK_SCALE : 1.0f;
        const size_t base = ((size_t)((b * 4 + head) * NSP + j)) * 32 + dbase;
        const u32 p01 = pk_f16(acc[mm][nt][0] * sc, acc[mm][nt][1] * sc);
        const u32 p23 = pk_f16(acc[mm][nt][2] * sc, acc[mm][nt][3] * sc);
        *(u32*)(dst + base)     = p01;
        *(u32*)(dst + base + 2) = p23;
      } else {
#pragma unroll
        for (int i = 0; i < 4; ++i)
          Vo[((size_t)((b * 4 + head) * 32 + dbase + i)) * NSP + j] =
              f16bits(acc[mm][nt][i]);
      }
    }
  }
}

// ---------------------------------------------------------------------------
// Kernel B: flash attention, swapped-operand MFMA form.
// grid 512 blocks x 256 threads (4 waves, 32 q-rows each), KV block = 64.
// S^T = mfma(K,Q): lane holds q-row (m*16+r), j = kv0 + n*16 + g*4 + i.
// O^T = mfma(V^T, P^T): lane holds O[q = m*16+r][dv = dn*16 + g*4 + i].
// P goes through XOR-swizzled wave-private LDS; K/V fragments direct global.
// No __syncthreads anywhere.
// ---------------------------------------------------------------------------
__global__ __launch_bounds__(256) void attn_kernel(
    const u16* __restrict__ Qg, const u16* __restrict__ Kg,
    const u16* __restrict__ Vg, float* __restrict__ att)
{
  __shared__ u16 P_lds[4 * 32 * 64];   // 16 KiB, wave-private 32x64 tiles

  // XCD swizzle: block d -> XCD d%8; give each XCD two full bh's.
  const int d  = blockIdx.x;
  const int bh = (d & 7) * 2 + ((d >> 3) & 1);
  const int qt = d >> 4;
  const int q0 = qt * 128;

  const int tid  = threadIdx.x;
  const int wave = tid >> 6, lane = tid & 63;
  const int g = lane >> 4, r = lane & 15;

  u16* Pw = P_lds + wave * 32 * 64;
  const f32x4 ZERO4 = {0.f, 0.f, 0.f, 0.f};

  const size_t qkbase = (size_t)bh * NSP * 32;
  const u16* Kp = Kg + qkbase;                  // [n][32]
  const u16* Vp = Vg + (size_t)bh * 32 * NSP;   // [32][n]

  f16x8 qf[2];
#pragma unroll
  for (int m = 0; m < 2; ++m)
    qf[m] = *(const f16x8*)(Qg + qkbase +
                            (size_t)(q0 + wave * 32 + m * 16 + r) * 32 + g * 8);

  f32x4 Oc[2][2];
  float mrun[2], lrun[2];
#pragma unroll
  for (int m = 0; m < 2; ++m) {
    Oc[m][0] = ZERO4; Oc[m][1] = ZERO4;
    mrun[m] = -INFINITY; lrun[m] = 0.f;
  }

  for (int t = 0; t < 64; ++t) {
    const int kv0 = t * 64;

    f16x8 kf[4];
#pragma unroll
    for (int n = 0; n < 4; ++n)
      kf[n] = *(const f16x8*)(Kp + (size_t)(kv0 + n * 16 + r) * 32 + g * 8);

    f16x8 vf[2][2];
#pragma unroll
    for (int dn = 0; dn < 2; ++dn)
#pragma unroll
      for (int kc = 0; kc < 2; ++kc)
        vf[dn][kc] = *(const f16x8*)(Vp + (size_t)(dn * 16 + r) * NSP +
                                     kv0 + kc * 32 + g * 8);

    f32x4 S[2][4];
#pragma unroll
    for (int m = 0; m < 2; ++m)
#pragma unroll
      for (int n = 0; n < 4; ++n)
        S[m][n] = MFMA_F16(kf[n], qf[m], ZERO4);

    // online softmax: one q-row per (lane, m)
#pragma unroll
    for (int m = 0; m < 2; ++m) {
      float t0 = fmaxf(fmaxf(S[m][0][0], S[m][0][1]), fmaxf(S[m][0][2], S[m][0][3]));
      float t1 = fmaxf(fmaxf(S[m][1][0], S[m][1][1]), fmaxf(S[m][1][2], S[m][1][3]));
      float t2 = fmaxf(fmaxf(S[m][2][0], S[m][2][1]), fmaxf(S[m][2][2], S[m][2][3]));
      float t3 = fmaxf(fmaxf(S[m][3][0], S[m][3][1]), fmaxf(S[m][3][2], S[m][3][3]));
      float tm = fmaxf(fmaxf(t0, t1), fmaxf(t2, t3));
      tm = fmaxf(tm, __shfl_xor(tm, 16));
      tm = fmaxf(tm, __shfl_xor(tm, 32));
      const float nm = fmaxf(mrun[m], tm);
      const float al = fexp2(mrun[m] - nm);
      mrun[m] = nm;

      const int row = m * 16 + r;
      float ps = 0.f;
#pragma unroll
      for (int n = 0; n < 4; ++n) {
        const float p0 = fexp2(S[m][n][0] - nm);
        const float p1 = fexp2(S[m][n][1] - nm);
        const float p2 = fexp2(S[m][n][2] - nm);
        const float p3 = fexp2(S[m][n][3] - nm);
        ps += (p0 + p1) + (p2 + p3);
        const int col = (n * 16 + g * 4) ^ ((row & 7) << 3);  // XOR swizzle
        uint2 pw;
        pw.x = pk_f16(p0, p1);
        pw.y = pk_f16(p2, p3);
        *(uint2*)(Pw + row * 64 + col) = pw;
      }
      ps += __shfl_xor(ps, 16);
      ps += __shfl_xor(ps, 32);
      lrun[m] = lrun[m] * al + ps;
#pragma unroll
      for (int dn = 0; dn < 2; ++dn)
#pragma unroll
        for (int i = 0; i < 4; ++i) Oc[m][dn][i] *= al;
    }

    // PV: O^T = V^T * P^T  (wave-private LDS; compiler inserts lgkmcnt)
#pragma unroll
    for (int m = 0; m < 2; ++m) {
      const int prow = m * 16 + r;
#pragma unroll
      for (int kc = 0; kc < 2; ++kc) {
        const int pcol = (kc * 32 + g * 8) ^ ((prow & 7) << 3);
        const f16x8 pf = *(const f16x8*)(Pw + prow * 64 + pcol);
#pragma unroll
        for (int dn = 0; dn < 2; ++dn)
          Oc[m][dn] = MFMA_F16(vf[dn][kc], pf, Oc[m][dn]);
      }
    }
  }

  // epilogue: att[b][q][h*32 + dv] fp32, float4 stores
  const int b = bh >> 2, h = bh & 3;
#pragma unroll
  for (int m = 0; m < 2; ++m) {
    const float inv = 1.0f / lrun[m];
    const int q = q0 + wave * 32 + m * 16 + r;
#pragma unroll
    for (int dn = 0; dn < 2; ++dn) {
      f32x4 o = Oc[m][dn];
      o[0] *= inv; o[1] *= inv; o[2] *= inv; o[3] *= inv;
      *(f32x4*)(att + ((size_t)(b * NSP + q)) * 128 + h * 32 + dn * 16 + g * 4) = o;
    }
  }
}

// ---------------------------------------------------------------------------
// Kernel C: output projection, fp32 VALU (keeps final stage exact).
// out[b][o][j] = bout[o] + sum_ch Wout[o][ch] * att[b][j][ch]
// grid (64 j-tiles, 2 o-halves, 4 b) x 256 threads; lanes = j (coalesced).
// ---------------------------------------------------------------------------
__global__ __launch_bounds__(256) void outproj_kernel(
    const float* __restrict__ att, const float* __restrict__ Wout,
    const float* __restrict__ bout, float* __restrict__ out)
{
  __shared__ float a_lds[64][129];   // pitch 129: conflict-free per-lane rows
  const int j0    = blockIdx.x * 64;
  const int ohalf = blockIdx.y;
  const int b     = blockIdx.z;
  const int tid   = threadIdx.x;

#pragma unroll
  for (int rep = 0; rep < 8; ++rep) {
    const int idx = tid + rep * 256;
    const int jj = idx >> 5;
    const int cc = (idx & 31) * 4;
    const float4 v = *(const float4*)(att + ((size_t)(b * NSP + j0 + jj)) * 128 + cc);
    a_lds[jj][cc + 0] = v.x;
    a_lds[jj][cc + 1] = v.y;
    a_lds[jj][cc + 2] = v.z;
    a_lds[jj][cc + 3] = v.w;
  }
  __syncthreads();

  const int lane = tid & 63;
  const int wv = __builtin_amdgcn_readfirstlane(tid >> 6);  // force SGPR
  const int o0 = ohalf * 128 + wv * 32;
  const int j = j0 + lane;

#pragma unroll
  for (int og = 0; og < 4; ++og) {
    const int ob = o0 + og * 8;
    float acc[8];
#pragma unroll
    for (int oo = 0; oo < 8; ++oo) acc[oo] = bout[ob + oo];
    for (int ch = 0; ch < 128; ch += 4) {
#pragma unroll
      for (int c2 = 0; c2 < 4; ++c2) {
        const float a = a_lds[lane][ch + c2];
#pragma unroll
        for (int oo = 0; oo < 8; ++oo)
          acc[oo] = fmaf(Wout[(ob + oo) * 128 + ch + c2], a, acc[oo]);
      }
    }
#pragma unroll
    for (int oo = 0; oo < 8; ++oo)
      out[((size_t)(b * 256 + ob + oo)) * NSP + j] = acc[oo];
  }
}

// ---------------------------------------------------------------------------
extern "C" void kernel_launch(void* const* d_in, const int* in_sizes, int n_in,
                              void* d_out, int out_size, void* d_ws, size_t ws_size,
                              hipStream_t stream) {
  const float* x    = (const float*)d_in[0];
  const float* Wq   = (const float*)d_in[1];
  const float* Wk   = (const float*)d_in[2];
  const float* Wv   = (const float*)d_in[3];
  const float* Wout = (const float*)d_in[4];
  const float* bout = (const float*)d_in[5];
  float* out = (float*)d_out;

  // workspace layout (20 MiB total)
  char* ws = (char*)d_ws;
  u16*   Qw  = (u16*)(ws);                    // 4 MiB  [16][4096][32] f16
  u16*   Kw  = (u16*)(ws + (4u << 20));       // 4 MiB  [16][4096][32] f16
  u16*   Vw  = (u16*)(ws + (8u << 20));       // 4 MiB  [16][32][4096] f16 (transposed)
  float* att = (float*)(ws + (12u << 20));    // 8 MiB  [4][4096][128] f32

  qkv_proj_kernel<<<dim3(64, 4), 512, 0, stream>>>(x, Wq, Wk, Wv, Qw, Kw, Vw);
  attn_kernel<<<dim3(512), 256, 0, stream>>>(Qw, Kw, Vw, att);
  outproj_kernel<<<dim3(64, 2, 4), 256, 0, stream>>>(att, Wout, bout, out);
}